// Round 2
// baseline (919.502 us; speedup 1.0000x reference)
//
#include <hip/hip_runtime.h>

// Problem constants (from reference): N=10000, D_IN=128, F1=F2=20, D_OUT=128
constexpr int NN   = 10000;
constexpr int DIN  = 128;
constexpr int F    = 20;       // F1 == F2 == 20
constexpr int DOUT = 128;

// adjmm tiling: block = 256 threads = 128 lane-pairs x 2 k-phases.
// Each lane-pair owns 4 rows (TM=512) so one t-read feeds 16 FMAs -> LDS
// traffic 2 GB/pass (under the 63 us HBM stream). KSPLIT=50 keeps grid at
// 1000 blocks (~4/CU).
constexpr int KSPLIT = 50;
constexpr int KRANGE = NN / KSPLIT;          // 200
constexpr int TM     = 512;                  // rows per block (4 per pair)
constexpr int RPT    = 4;                    // rows per thread
constexpr int ROWBLK = (NN + TM - 1) / TM;   // 20
constexpr int NFLT4  = NN * F / 4;           // 50000 float4 in an NxF buffer

// ---------------------------------------------------------------------------
// out[i,f] = sum_k x[i,k] * W[k,f]   (K=128, F=20)  -> t1
// ---------------------------------------------------------------------------
__global__ __launch_bounds__(256) void gemm_x_w1(const float* __restrict__ x,
                                                 const float* __restrict__ W,
                                                 float* __restrict__ out) {
    int t = blockIdx.x * 256 + threadIdx.x;
    if (t >= NN * F) return;
    int i = t / F, f = t % F;
    const float4* xp = (const float4*)(x + (size_t)i * DIN);
    float s = 0.f;
#pragma unroll
    for (int k4 = 0; k4 < DIN / 4; ++k4) {
        float4 xv = xp[k4];
        int k = k4 * 4;
        s += xv.x * W[(k + 0) * F + f];
        s += xv.y * W[(k + 1) * F + f];
        s += xv.z * W[(k + 2) * F + f];
        s += xv.w * W[(k + 3) * F + f];
    }
    out[t] = s;
}

// ---------------------------------------------------------------------------
// out[i,g] = sum_f in[i,f] * W[f,g]   (K=20, F=20)
// ---------------------------------------------------------------------------
__global__ __launch_bounds__(256) void gemm_h_w2(const float* __restrict__ h,
                                                 const float* __restrict__ W,
                                                 float* __restrict__ out) {
    int t = blockIdx.x * 256 + threadIdx.x;
    if (t >= NN * F) return;
    int i = t / F, g = t % F;
    const float* hp = h + (size_t)i * F;
    float s = 0.f;
#pragma unroll
    for (int f = 0; f < F; ++f) s += hp[f] * W[f * F + g];
    out[t] = s;
}

// ---------------------------------------------------------------------------
// bias+relu (atomic-fallback path only)
// ---------------------------------------------------------------------------
__global__ __launch_bounds__(256) void bias_relu(const float* __restrict__ in,
                                                 const float* __restrict__ b,
                                                 float* __restrict__ out) {
    int t = blockIdx.x * 256 + threadIdx.x;
    if (t >= NN * F) return;
    out[t] = fmaxf(in[t] + b[t % F], 0.f);
}

// ---------------------------------------------------------------------------
// adjmm: out_partial[by, i, :F] = adj[i, k-range(by)] @ t[k-range(by), :F]
//
// - t slice (KRANGE x F = 16 KB) staged once into LDS; inner-loop t reads are
//   2-distinct-address LDS broadcasts (2-way = free), each feeding 4 rows
//   (16 FMA per ds_read_b128 -> DS pipe ~38 us/pass, under HBM).
// - adj streamed from global: lane pair (2r, 2r+1) covers 32 B contiguous per
//   row, sequential across m -> full-line consumption, ideal coalescing.
// - One barrier per block, no per-tile vmcnt drains.
// - PART=1: per-ksplit partials (no atomic RMW). PART=0: atomicAdd fallback.
// - REV=1: reverse traversal to reuse the adj tail left in L3 by the
//   previous dispatch.
// ---------------------------------------------------------------------------
template <int REV, int PART>
__global__ __launch_bounds__(256) void adjmm(const float* __restrict__ adj,
                                             const float* __restrict__ t,
                                             float* __restrict__ out) {
    __shared__ __align__(16) float tl[KRANGE * F];   // 16000 B

    const int tid = threadIdx.x;
    const int bx = REV ? ((int)gridDim.x - 1 - (int)blockIdx.x) : (int)blockIdx.x;
    const int by = REV ? ((int)gridDim.y - 1 - (int)blockIdx.y) : (int)blockIdx.y;
    const int row0 = bx * TM;
    const int k0   = by * KRANGE;

    // stage t[k0 .. k0+KRANGE)[0..F) -> LDS : 1000 float4, contiguous
    {
        const float4* src = (const float4*)(t + (size_t)k0 * F);
        float4* dst = (float4*)tl;
#pragma unroll
        for (int i = 0; i < 4; ++i) {
            int idx = tid + i * 256;
            if (idx < KRANGE * F / 4) dst[idx] = src[idx];
        }
    }
    __syncthreads();

    const int r = tid >> 1;          // 0..127 : pair index
    const int p = tid & 1;           // k-phase

    int   rows[RPT];
    bool  ok[RPT];
    const float4* ap[RPT];
#pragma unroll
    for (int c = 0; c < RPT; ++c) {
        int row = row0 + r + c * 128;
        ok[c]   = row < NN;
        rows[c] = ok[c] ? row : (NN - 1);   // clamp: loads stay in-bounds
        ap[c]   = (const float4*)(adj + (size_t)rows[c] * NN + k0);
    }

    float4 acc[RPT][5];
#pragma unroll
    for (int c = 0; c < RPT; ++c)
#pragma unroll
        for (int q = 0; q < 5; ++q) acc[c][q] = make_float4(0.f, 0.f, 0.f, 0.f);

    constexpr int M = KRANGE / 8;    // 25
#pragma unroll 2
    for (int m = 0; m < M; ++m) {
        const int mm = REV ? (M - 1 - m) : m;
        float4 a[RPT];
#pragma unroll
        for (int c = 0; c < RPT; ++c) a[c] = ap[c][2 * mm + p];   // 4 k's, this phase
#pragma unroll
        for (int j = 0; j < 4; ++j) {
            const float4* tp = (const float4*)(tl + (8 * mm + 4 * p + j) * F);
            float4 tv0 = tp[0], tv1 = tp[1], tv2 = tp[2], tv3 = tp[3], tv4 = tp[4];
#pragma unroll
            for (int c = 0; c < RPT; ++c) {
                const float aj = (j == 0) ? a[c].x : (j == 1) ? a[c].y
                               : (j == 2) ? a[c].z : a[c].w;
                acc[c][0].x += aj * tv0.x; acc[c][0].y += aj * tv0.y;
                acc[c][0].z += aj * tv0.z; acc[c][0].w += aj * tv0.w;
                acc[c][1].x += aj * tv1.x; acc[c][1].y += aj * tv1.y;
                acc[c][1].z += aj * tv1.z; acc[c][1].w += aj * tv1.w;
                acc[c][2].x += aj * tv2.x; acc[c][2].y += aj * tv2.y;
                acc[c][2].z += aj * tv2.z; acc[c][2].w += aj * tv2.w;
                acc[c][3].x += aj * tv3.x; acc[c][3].y += aj * tv3.y;
                acc[c][3].z += aj * tv3.z; acc[c][3].w += aj * tv3.w;
                acc[c][4].x += aj * tv4.x; acc[c][4].y += aj * tv4.y;
                acc[c][4].z += aj * tv4.z; acc[c][4].w += aj * tv4.w;
            }
        }
    }

    // combine the two phase lanes (partner lane always active: same rows)
#pragma unroll
    for (int c = 0; c < RPT; ++c)
#pragma unroll
        for (int q = 0; q < 5; ++q) {
            acc[c][q].x += __shfl_xor(acc[c][q].x, 1);
            acc[c][q].y += __shfl_xor(acc[c][q].y, 1);
            acc[c][q].z += __shfl_xor(acc[c][q].z, 1);
            acc[c][q].w += __shfl_xor(acc[c][q].w, 1);
        }

    if (p == 0) {
        if (PART) {
#pragma unroll
            for (int c = 0; c < RPT; ++c) {
                if (!ok[c]) continue;
                float4* op = (float4*)(out + ((size_t)by * NN + rows[c]) * F);
#pragma unroll
                for (int q = 0; q < 5; ++q) op[q] = acc[c][q];
            }
        } else {
#pragma unroll
            for (int c = 0; c < RPT; ++c) {
                if (!ok[c]) continue;
                float* op = out + (size_t)rows[c] * F;
#pragma unroll
                for (int q = 0; q < 5; ++q) {
                    atomicAdd(op + q * 4 + 0, acc[c][q].x);
                    atomicAdd(op + q * 4 + 1, acc[c][q].y);
                    atomicAdd(op + q * 4 + 2, acc[c][q].z);
                    atomicAdd(op + q * 4 + 3, acc[c][q].w);
                }
            }
        }
    }
}

// ---------------------------------------------------------------------------
// reduce the KSPLIT partial buffers; optionally fuse bias+relu.
// ---------------------------------------------------------------------------
template <int BIASRELU>
__global__ __launch_bounds__(256) void reduce_p(const float* __restrict__ P,
                                                const float* __restrict__ b,
                                                float* __restrict__ out) {
    int t = blockIdx.x * 256 + threadIdx.x;
    if (t >= NFLT4) return;
    float4 s = ((const float4*)P)[t];
    for (int k = 1; k < KSPLIT; ++k) {
        float4 v = ((const float4*)P)[(size_t)k * NFLT4 + t];
        s.x += v.x; s.y += v.y; s.z += v.z; s.w += v.w;
    }
    if (BIASRELU) {
        int f4 = t % (F / 4);
        float4 bv = ((const float4*)b)[f4];
        s.x = fmaxf(s.x + bv.x, 0.f);
        s.y = fmaxf(s.y + bv.y, 0.f);
        s.z = fmaxf(s.z + bv.z, 0.f);
        s.w = fmaxf(s.w + bv.w, 0.f);
    }
    ((float4*)out)[t] = s;
}

// ---------------------------------------------------------------------------
// out[i,f] = relu( relu( sum_g u[i,g]*W3[g,f] + b3[f] ) + x[i,f] )
// ---------------------------------------------------------------------------
__global__ __launch_bounds__(256) void final_fuse(const float* __restrict__ u,
                                                  const float* __restrict__ W3,
                                                  const float* __restrict__ b3,
                                                  const float* __restrict__ x,
                                                  float* __restrict__ out) {
    int t = blockIdx.x * 256 + threadIdx.x;
    if (t >= NN * DOUT) return;
    int i = t / DOUT, f = t % DOUT;
    const float* up = u + (size_t)i * F;
    float s = b3[f];
#pragma unroll
    for (int g = 0; g < F; ++g) s += up[g] * W3[g * DOUT + f];
    float h = fmaxf(s, 0.f);
    out[t] = fmaxf(h + x[t], 0.f);
}

// ---------------------------------------------------------------------------
extern "C" void kernel_launch(void* const* d_in, const int* in_sizes, int n_in,
                              void* d_out, int out_size, void* d_ws, size_t ws_size,
                              hipStream_t stream) {
    const float* x   = (const float*)d_in[0];
    const float* adj = (const float*)d_in[1];
    const float* W1  = (const float*)d_in[2];
    const float* b1  = (const float*)d_in[3];
    const float* W2  = (const float*)d_in[4];
    const float* b2  = (const float*)d_in[5];
    const float* W3  = (const float*)d_in[6];
    const float* b3  = (const float*)d_in[7];
    float* out = (float*)d_out;

    float* A = (float*)d_ws;            // N x F
    float* C = A + (size_t)NN * F;      // N x F
    float* P = C + (size_t)NN * F;      // KSPLIT x N x F partials (40 MB)
    const size_t nf_bytes = (size_t)NN * F * sizeof(float);
    const size_t need = nf_bytes * (2 + KSPLIT);

    const int blk_nf  = (NN * F + 255) / 256;        // 782
    const int blk_nf4 = (NFLT4 + 255) / 256;         // 196
    const int blk_no  = (NN * DOUT + 255) / 256;     // 5000
    dim3 agrid(ROWBLK, KSPLIT);                      // 20 x 50 = 1000 blocks

    if (ws_size >= need) {
        // Layer 1: h1 = relu(adj @ (x@W1) + b1)
        gemm_x_w1<<<blk_nf, 256, 0, stream>>>(x, W1, A);
        adjmm<0, 1><<<agrid, 256, 0, stream>>>(adj, A, P);
        reduce_p<1><<<blk_nf4, 256, 0, stream>>>(P, b1, C);

        // Layer 2: h2 = relu(adj @ (h1@W2) + b2)   (adj streamed in reverse)
        gemm_h_w2<<<blk_nf, 256, 0, stream>>>(C, W2, A);
        adjmm<1, 1><<<agrid, 256, 0, stream>>>(adj, A, P);
        reduce_p<1><<<blk_nf4, 256, 0, stream>>>(P, b2, C);

        // Layer 3 (reassociated): u = adj @ h2 ; out = relu(relu(u@W3+b3)+x)
        adjmm<0, 1><<<agrid, 256, 0, stream>>>(adj, C, P);
        reduce_p<0><<<blk_nf4, 256, 0, stream>>>(P, nullptr, A);
        final_fuse<<<blk_no, 256, 0, stream>>>(A, W3, b3, x, out);
    } else {
        // Fallback: atomic accumulation (3 NxF buffers only)
        float* B = P;  // only NxF of it used
        gemm_x_w1<<<blk_nf, 256, 0, stream>>>(x, W1, A);
        hipMemsetAsync(B, 0, nf_bytes, stream);
        adjmm<0, 0><<<agrid, 256, 0, stream>>>(adj, A, B);
        bias_relu<<<blk_nf, 256, 0, stream>>>(B, b1, C);

        gemm_h_w2<<<blk_nf, 256, 0, stream>>>(C, W2, A);
        hipMemsetAsync(B, 0, nf_bytes, stream);
        adjmm<1, 0><<<agrid, 256, 0, stream>>>(adj, A, B);
        bias_relu<<<blk_nf, 256, 0, stream>>>(B, b2, C);

        hipMemsetAsync(A, 0, nf_bytes, stream);
        adjmm<0, 0><<<agrid, 256, 0, stream>>>(adj, C, A);
        final_fuse<<<blk_no, 256, 0, stream>>>(A, W3, b3, x, out);
    }
}

// Round 3
// 901.188 us; speedup vs baseline: 1.0203x; 1.0203x over previous
//
#include <hip/hip_runtime.h>

// Problem constants (from reference): N=10000, D_IN=128, F1=F2=20, D_OUT=128
constexpr int NN   = 10000;
constexpr int DIN  = 128;
constexpr int F    = 20;       // F1 == F2 == 20
constexpr int DOUT = 128;

// adjmm tiling: block = 256 threads = 128 lane-pairs x 2 k-phases.
// RPT=2: each lane-pair owns 2 rows -> one t-read feeds 8 FMAs (DS traffic
// 4 GB/pass ~77us floor) while VGPRs stay ~100-115 (acc 40 + tv 20 + a 8)
// so occupancy holds at >=4 waves/SIMD. (RPT=4 regressed: ~170+ VGPR,
// 2 waves/SIMD, scattered adj loads unhidden.)
constexpr int KSPLIT = 25;
constexpr int KRANGE = NN / KSPLIT;          // 400
constexpr int TM     = 256;                  // rows per block (2 per pair)
constexpr int RPT    = 2;                    // rows per thread
constexpr int ROWBLK = (NN + TM - 1) / TM;   // 40
constexpr int NFLT4  = NN * F / 4;           // 50000 float4 in an NxF buffer

// ---------------------------------------------------------------------------
// out[i,f] = sum_k x[i,k] * W[k,f]   (K=128, F=20)  -> t1
// ---------------------------------------------------------------------------
__global__ __launch_bounds__(256) void gemm_x_w1(const float* __restrict__ x,
                                                 const float* __restrict__ W,
                                                 float* __restrict__ out) {
    int t = blockIdx.x * 256 + threadIdx.x;
    if (t >= NN * F) return;
    int i = t / F, f = t % F;
    const float4* xp = (const float4*)(x + (size_t)i * DIN);
    float s = 0.f;
#pragma unroll
    for (int k4 = 0; k4 < DIN / 4; ++k4) {
        float4 xv = xp[k4];
        int k = k4 * 4;
        s += xv.x * W[(k + 0) * F + f];
        s += xv.y * W[(k + 1) * F + f];
        s += xv.z * W[(k + 2) * F + f];
        s += xv.w * W[(k + 3) * F + f];
    }
    out[t] = s;
}

// ---------------------------------------------------------------------------
// out[i,g] = sum_f in[i,f] * W[f,g]   (K=20, F=20)
// ---------------------------------------------------------------------------
__global__ __launch_bounds__(256) void gemm_h_w2(const float* __restrict__ h,
                                                 const float* __restrict__ W,
                                                 float* __restrict__ out) {
    int t = blockIdx.x * 256 + threadIdx.x;
    if (t >= NN * F) return;
    int i = t / F, g = t % F;
    const float* hp = h + (size_t)i * F;
    float s = 0.f;
#pragma unroll
    for (int f = 0; f < F; ++f) s += hp[f] * W[f * F + g];
    out[t] = s;
}

// ---------------------------------------------------------------------------
// bias+relu (atomic-fallback path only)
// ---------------------------------------------------------------------------
__global__ __launch_bounds__(256) void bias_relu(const float* __restrict__ in,
                                                 const float* __restrict__ b,
                                                 float* __restrict__ out) {
    int t = blockIdx.x * 256 + threadIdx.x;
    if (t >= NN * F) return;
    out[t] = fmaxf(in[t] + b[t % F], 0.f);
}

// ---------------------------------------------------------------------------
// adjmm: out_partial[by, i, :F] = adj[i, k-range(by)] @ t[k-range(by), :F]
//
// - t slice (KRANGE x F = 32 KB) staged once into LDS; inner-loop t reads are
//   2-distinct-address LDS broadcasts (2-way = free), each feeding RPT rows.
// - adj streamed from global: lane pair (2r, 2r+1) covers 32 B contiguous per
//   row, sequential across m -> full-line consumption over 4 m-steps.
// - One barrier per block, no per-tile vmcnt drains.
// - PART=1: per-ksplit partials (no atomic RMW). PART=0: atomicAdd fallback.
// - REV=1: reverse traversal to reuse the adj tail left in L3 by the
//   previous dispatch.
// ---------------------------------------------------------------------------
template <int REV, int PART>
__global__ __launch_bounds__(256, 3) void adjmm(const float* __restrict__ adj,
                                                const float* __restrict__ t,
                                                float* __restrict__ out) {
    __shared__ __align__(16) float tl[KRANGE * F];   // 32000 B

    const int tid = threadIdx.x;
    const int bx = REV ? ((int)gridDim.x - 1 - (int)blockIdx.x) : (int)blockIdx.x;
    const int by = REV ? ((int)gridDim.y - 1 - (int)blockIdx.y) : (int)blockIdx.y;
    const int row0 = bx * TM;
    const int k0   = by * KRANGE;

    // stage t[k0 .. k0+KRANGE)[0..F) -> LDS : 2000 float4, contiguous
    {
        const float4* src = (const float4*)(t + (size_t)k0 * F);
        float4* dst = (float4*)tl;
#pragma unroll
        for (int i = 0; i < 8; ++i) {
            int idx = tid + i * 256;
            if (idx < KRANGE * F / 4) dst[idx] = src[idx];
        }
    }
    __syncthreads();

    const int r = tid >> 1;          // 0..127 : pair index
    const int p = tid & 1;           // k-phase

    int   rows[RPT];
    bool  ok[RPT];
    const float4* ap[RPT];
#pragma unroll
    for (int c = 0; c < RPT; ++c) {
        int row = row0 + r + c * 128;
        ok[c]   = row < NN;
        rows[c] = ok[c] ? row : (NN - 1);   // clamp: loads stay in-bounds
        ap[c]   = (const float4*)(adj + (size_t)rows[c] * NN + k0);
    }

    float4 acc[RPT][5];
#pragma unroll
    for (int c = 0; c < RPT; ++c)
#pragma unroll
        for (int q = 0; q < 5; ++q) acc[c][q] = make_float4(0.f, 0.f, 0.f, 0.f);

    constexpr int M = KRANGE / 8;    // 50
    for (int m = 0; m < M; ++m) {
        const int mm = REV ? (M - 1 - m) : m;
        float4 a[RPT];
#pragma unroll
        for (int c = 0; c < RPT; ++c) a[c] = ap[c][2 * mm + p];   // 4 k's, this phase
#pragma unroll
        for (int j = 0; j < 4; ++j) {
            const float4* tp = (const float4*)(tl + (8 * mm + 4 * p + j) * F);
            float4 tv0 = tp[0], tv1 = tp[1], tv2 = tp[2], tv3 = tp[3], tv4 = tp[4];
#pragma unroll
            for (int c = 0; c < RPT; ++c) {
                const float aj = (j == 0) ? a[c].x : (j == 1) ? a[c].y
                               : (j == 2) ? a[c].z : a[c].w;
                acc[c][0].x += aj * tv0.x; acc[c][0].y += aj * tv0.y;
                acc[c][0].z += aj * tv0.z; acc[c][0].w += aj * tv0.w;
                acc[c][1].x += aj * tv1.x; acc[c][1].y += aj * tv1.y;
                acc[c][1].z += aj * tv1.z; acc[c][1].w += aj * tv1.w;
                acc[c][2].x += aj * tv2.x; acc[c][2].y += aj * tv2.y;
                acc[c][2].z += aj * tv2.z; acc[c][2].w += aj * tv2.w;
                acc[c][3].x += aj * tv3.x; acc[c][3].y += aj * tv3.y;
                acc[c][3].z += aj * tv3.z; acc[c][3].w += aj * tv3.w;
                acc[c][4].x += aj * tv4.x; acc[c][4].y += aj * tv4.y;
                acc[c][4].z += aj * tv4.z; acc[c][4].w += aj * tv4.w;
            }
        }
    }

    // combine the two phase lanes (partner lane always active: same rows)
#pragma unroll
    for (int c = 0; c < RPT; ++c)
#pragma unroll
        for (int q = 0; q < 5; ++q) {
            acc[c][q].x += __shfl_xor(acc[c][q].x, 1);
            acc[c][q].y += __shfl_xor(acc[c][q].y, 1);
            acc[c][q].z += __shfl_xor(acc[c][q].z, 1);
            acc[c][q].w += __shfl_xor(acc[c][q].w, 1);
        }

    if (p == 0) {
        if (PART) {
#pragma unroll
            for (int c = 0; c < RPT; ++c) {
                if (!ok[c]) continue;
                float4* op = (float4*)(out + ((size_t)by * NN + rows[c]) * F);
#pragma unroll
                for (int q = 0; q < 5; ++q) op[q] = acc[c][q];
            }
        } else {
#pragma unroll
            for (int c = 0; c < RPT; ++c) {
                if (!ok[c]) continue;
                float* op = out + (size_t)rows[c] * F;
#pragma unroll
                for (int q = 0; q < 5; ++q) {
                    atomicAdd(op + q * 4 + 0, acc[c][q].x);
                    atomicAdd(op + q * 4 + 1, acc[c][q].y);
                    atomicAdd(op + q * 4 + 2, acc[c][q].z);
                    atomicAdd(op + q * 4 + 3, acc[c][q].w);
                }
            }
        }
    }
}

// ---------------------------------------------------------------------------
// reduce the KSPLIT partial buffers; optionally fuse bias+relu.
// ---------------------------------------------------------------------------
template <int BIASRELU>
__global__ __launch_bounds__(256) void reduce_p(const float* __restrict__ P,
                                                const float* __restrict__ b,
                                                float* __restrict__ out) {
    int t = blockIdx.x * 256 + threadIdx.x;
    if (t >= NFLT4) return;
    float4 s = ((const float4*)P)[t];
    for (int k = 1; k < KSPLIT; ++k) {
        float4 v = ((const float4*)P)[(size_t)k * NFLT4 + t];
        s.x += v.x; s.y += v.y; s.z += v.z; s.w += v.w;
    }
    if (BIASRELU) {
        int f4 = t % (F / 4);
        float4 bv = ((const float4*)b)[f4];
        s.x = fmaxf(s.x + bv.x, 0.f);
        s.y = fmaxf(s.y + bv.y, 0.f);
        s.z = fmaxf(s.z + bv.z, 0.f);
        s.w = fmaxf(s.w + bv.w, 0.f);
    }
    ((float4*)out)[t] = s;
}

// ---------------------------------------------------------------------------
// out[i,f] = relu( relu( sum_g u[i,g]*W3[g,f] + b3[f] ) + x[i,f] )
// ---------------------------------------------------------------------------
__global__ __launch_bounds__(256) void final_fuse(const float* __restrict__ u,
                                                  const float* __restrict__ W3,
                                                  const float* __restrict__ b3,
                                                  const float* __restrict__ x,
                                                  float* __restrict__ out) {
    int t = blockIdx.x * 256 + threadIdx.x;
    if (t >= NN * DOUT) return;
    int i = t / DOUT, f = t % DOUT;
    const float* up = u + (size_t)i * F;
    float s = b3[f];
#pragma unroll
    for (int g = 0; g < F; ++g) s += up[g] * W3[g * DOUT + f];
    float h = fmaxf(s, 0.f);
    out[t] = fmaxf(h + x[t], 0.f);
}

// ---------------------------------------------------------------------------
extern "C" void kernel_launch(void* const* d_in, const int* in_sizes, int n_in,
                              void* d_out, int out_size, void* d_ws, size_t ws_size,
                              hipStream_t stream) {
    const float* x   = (const float*)d_in[0];
    const float* adj = (const float*)d_in[1];
    const float* W1  = (const float*)d_in[2];
    const float* b1  = (const float*)d_in[3];
    const float* W2  = (const float*)d_in[4];
    const float* b2  = (const float*)d_in[5];
    const float* W3  = (const float*)d_in[6];
    const float* b3  = (const float*)d_in[7];
    float* out = (float*)d_out;

    float* A = (float*)d_ws;            // N x F
    float* C = A + (size_t)NN * F;      // N x F
    float* P = C + (size_t)NN * F;      // KSPLIT x N x F partials (20 MB)
    const size_t nf_bytes = (size_t)NN * F * sizeof(float);
    const size_t need = nf_bytes * (2 + KSPLIT);

    const int blk_nf  = (NN * F + 255) / 256;        // 782
    const int blk_nf4 = (NFLT4 + 255) / 256;         // 196
    const int blk_no  = (NN * DOUT + 255) / 256;     // 5000
    dim3 agrid(ROWBLK, KSPLIT);                      // 40 x 25 = 1000 blocks

    if (ws_size >= need) {
        // Layer 1: h1 = relu(adj @ (x@W1) + b1)
        gemm_x_w1<<<blk_nf, 256, 0, stream>>>(x, W1, A);
        adjmm<0, 1><<<agrid, 256, 0, stream>>>(adj, A, P);
        reduce_p<1><<<blk_nf4, 256, 0, stream>>>(P, b1, C);

        // Layer 2: h2 = relu(adj @ (h1@W2) + b2)   (adj streamed in reverse)
        gemm_h_w2<<<blk_nf, 256, 0, stream>>>(C, W2, A);
        adjmm<1, 1><<<agrid, 256, 0, stream>>>(adj, A, P);
        reduce_p<1><<<blk_nf4, 256, 0, stream>>>(P, b2, C);

        // Layer 3 (reassociated): u = adj @ h2 ; out = relu(relu(u@W3+b3)+x)
        adjmm<0, 1><<<agrid, 256, 0, stream>>>(adj, C, P);
        reduce_p<0><<<blk_nf4, 256, 0, stream>>>(P, nullptr, A);
        final_fuse<<<blk_no, 256, 0, stream>>>(A, W3, b3, x, out);
    } else {
        // Fallback: atomic accumulation (3 NxF buffers only)
        float* B = P;  // only NxF of it used
        gemm_x_w1<<<blk_nf, 256, 0, stream>>>(x, W1, A);
        hipMemsetAsync(B, 0, nf_bytes, stream);
        adjmm<0, 0><<<agrid, 256, 0, stream>>>(adj, A, B);
        bias_relu<<<blk_nf, 256, 0, stream>>>(B, b1, C);

        gemm_h_w2<<<blk_nf, 256, 0, stream>>>(C, W2, A);
        hipMemsetAsync(B, 0, nf_bytes, stream);
        adjmm<1, 0><<<agrid, 256, 0, stream>>>(adj, A, B);
        bias_relu<<<blk_nf, 256, 0, stream>>>(B, b2, C);

        hipMemsetAsync(A, 0, nf_bytes, stream);
        adjmm<0, 0><<<agrid, 256, 0, stream>>>(adj, C, A);
        final_fuse<<<blk_no, 256, 0, stream>>>(A, W3, b3, x, out);
    }
}

// Round 4
// 839.030 us; speedup vs baseline: 1.0959x; 1.0741x over previous
//
#include <hip/hip_runtime.h>

// Problem constants (from reference): N=10000, D_IN=128, F1=F2=20, D_OUT=128
constexpr int NN   = 10000;
constexpr int DIN  = 128;
constexpr int F    = 20;       // F1 == F2 == 20
constexpr int DOUT = 128;

// adjmm tiling: block = 256 threads = 128 lane-pairs x 2 k-phases, RPT=1
// (RPT sweep measured: 1 -> 812us, 2 -> 901, 4 -> 919 total; occupancy wins).
// KSPLIT=50: t-slice 16KB LDS, 3950 blocks. Latency hidden by explicit
// 5-deep register prefetch of adj (chunk = 5 m-iters), not by TLP.
constexpr int KSPLIT = 50;
constexpr int KRANGE = NN / KSPLIT;          // 200
constexpr int TM     = 128;                  // rows per block (1 per pair)
constexpr int ROWBLK = (NN + TM - 1) / TM;   // 79
constexpr int NFLT4  = NN * F / 4;           // 50000 float4 in an NxF buffer
constexpr int M      = KRANGE / 8;           // 25 m-iters (8 k's per m)
constexpr int CH     = 5;                    // m-iters per prefetch chunk
constexpr int NCHUNK = M / CH;               // 5

// ---------------------------------------------------------------------------
// out[i,f] = sum_k x[i,k] * W[k,f]   (K=128, F=20)  -> t1
// ---------------------------------------------------------------------------
__global__ __launch_bounds__(256) void gemm_x_w1(const float* __restrict__ x,
                                                 const float* __restrict__ W,
                                                 float* __restrict__ out) {
    int t = blockIdx.x * 256 + threadIdx.x;
    if (t >= NN * F) return;
    int i = t / F, f = t % F;
    const float4* xp = (const float4*)(x + (size_t)i * DIN);
    float s = 0.f;
#pragma unroll
    for (int k4 = 0; k4 < DIN / 4; ++k4) {
        float4 xv = xp[k4];
        int k = k4 * 4;
        s += xv.x * W[(k + 0) * F + f];
        s += xv.y * W[(k + 1) * F + f];
        s += xv.z * W[(k + 2) * F + f];
        s += xv.w * W[(k + 3) * F + f];
    }
    out[t] = s;
}

// ---------------------------------------------------------------------------
// out[i,g] = sum_f in[i,f] * W[f,g]   (K=20, F=20)
// ---------------------------------------------------------------------------
__global__ __launch_bounds__(256) void gemm_h_w2(const float* __restrict__ h,
                                                 const float* __restrict__ W,
                                                 float* __restrict__ out) {
    int t = blockIdx.x * 256 + threadIdx.x;
    if (t >= NN * F) return;
    int i = t / F, g = t % F;
    const float* hp = h + (size_t)i * F;
    float s = 0.f;
#pragma unroll
    for (int f = 0; f < F; ++f) s += hp[f] * W[f * F + g];
    out[t] = s;
}

// ---------------------------------------------------------------------------
// bias+relu (atomic-fallback path only)
// ---------------------------------------------------------------------------
__global__ __launch_bounds__(256) void bias_relu(const float* __restrict__ in,
                                                 const float* __restrict__ b,
                                                 float* __restrict__ out) {
    int t = blockIdx.x * 256 + threadIdx.x;
    if (t >= NN * F) return;
    out[t] = fmaxf(in[t] + b[t % F], 0.f);
}

// ---------------------------------------------------------------------------
// adjmm: out_partial[by, i, :F] = adj[i, k-range(by)] @ t[k-range(by), :F]
//
// - t slice (200 x 20 = 16 KB) staged once into LDS; inner t reads are
//   2-distinct-address LDS broadcasts (conflict-free).
// - adj streamed from global, lane pair covers 32 B contiguous per row.
// - Explicit 5-deep prefetch: chunk c+1's 5 adj float4 loads issued before
//   consuming chunk c -> ~5 KB in flight per wave, HBM/L2 latency hidden by
//   ILP (VGPR ~95, launch_bounds(256,4): no spill risk).
// - PART=1: per-ksplit partials (no atomic RMW). PART=0: atomicAdd fallback.
// - REV=1: reverse traversal to reuse adj left in L3 by previous dispatch.
// ---------------------------------------------------------------------------
template <int REV, int PART>
__global__ __launch_bounds__(256, 4) void adjmm(const float* __restrict__ adj,
                                                const float* __restrict__ t,
                                                float* __restrict__ out) {
    __shared__ __align__(16) float tl[KRANGE * F];   // 16000 B

    const int tid = threadIdx.x;
    const int bx = REV ? ((int)gridDim.x - 1 - (int)blockIdx.x) : (int)blockIdx.x;
    const int by = REV ? ((int)gridDim.y - 1 - (int)blockIdx.y) : (int)blockIdx.y;
    const int row0 = bx * TM;
    const int k0   = by * KRANGE;

    // stage t[k0 .. k0+KRANGE)[0..F) -> LDS : 1000 float4, contiguous
    {
        const float4* src = (const float4*)(t + (size_t)k0 * F);
        float4* dst = (float4*)tl;
#pragma unroll
        for (int i = 0; i < 4; ++i) {
            int idx = tid + i * 256;
            if (idx < KRANGE * F / 4) dst[idx] = src[idx];
        }
    }
    __syncthreads();

    const int r = tid >> 1;          // 0..127 : pair index = row offset
    const int p = tid & 1;           // k-phase
    const int row  = row0 + r;
    const bool ok  = row < NN;
    const int rowc = ok ? row : (NN - 1);   // clamp: loads stay in-bounds

    const float4* ap = (const float4*)(adj + (size_t)rowc * NN + k0);

    float4 acc[5];
#pragma unroll
    for (int q = 0; q < 5; ++q) acc[q] = make_float4(0.f, 0.f, 0.f, 0.f);

    // m-index for chunk c, slot i (REV flips traversal order)
    auto MIDX = [&](int c, int i) -> int {
        int m = c * CH + i;
        return REV ? (M - 1 - m) : m;
    };

    float4 aC[CH], aN[CH];
    // prologue: load chunk 0
#pragma unroll
    for (int i = 0; i < CH; ++i) aC[i] = ap[2 * MIDX(0, i) + p];

#pragma unroll
    for (int c = 0; c < NCHUNK; ++c) {
        // issue next chunk's loads first (independent, 5 in flight)
        if (c + 1 < NCHUNK) {
#pragma unroll
            for (int i = 0; i < CH; ++i) aN[i] = ap[2 * MIDX(c + 1, i) + p];
        }
        // consume current chunk
#pragma unroll
        for (int i = 0; i < CH; ++i) {
            const int mm = MIDX(c, i);
            const float4 a = aC[i];
#pragma unroll
            for (int j = 0; j < 4; ++j) {
                const float aj = (j == 0) ? a.x : (j == 1) ? a.y
                               : (j == 2) ? a.z : a.w;
                const float4* tp = (const float4*)(tl + (8 * mm + 4 * p + j) * F);
                float4 tv0 = tp[0], tv1 = tp[1], tv2 = tp[2], tv3 = tp[3], tv4 = tp[4];
                acc[0].x += aj * tv0.x; acc[0].y += aj * tv0.y;
                acc[0].z += aj * tv0.z; acc[0].w += aj * tv0.w;
                acc[1].x += aj * tv1.x; acc[1].y += aj * tv1.y;
                acc[1].z += aj * tv1.z; acc[1].w += aj * tv1.w;
                acc[2].x += aj * tv2.x; acc[2].y += aj * tv2.y;
                acc[2].z += aj * tv2.z; acc[2].w += aj * tv2.w;
                acc[3].x += aj * tv3.x; acc[3].y += aj * tv3.y;
                acc[3].z += aj * tv3.z; acc[3].w += aj * tv3.w;
                acc[4].x += aj * tv4.x; acc[4].y += aj * tv4.y;
                acc[4].z += aj * tv4.z; acc[4].w += aj * tv4.w;
            }
        }
#pragma unroll
        for (int i = 0; i < CH; ++i) aC[i] = aN[i];
    }

    // combine the two phase lanes (partner lane always active: same row)
#pragma unroll
    for (int q = 0; q < 5; ++q) {
        acc[q].x += __shfl_xor(acc[q].x, 1);
        acc[q].y += __shfl_xor(acc[q].y, 1);
        acc[q].z += __shfl_xor(acc[q].z, 1);
        acc[q].w += __shfl_xor(acc[q].w, 1);
    }

    if (p == 0 && ok) {
        if (PART) {
            float4* op = (float4*)(out + ((size_t)by * NN + row) * F);
#pragma unroll
            for (int q = 0; q < 5; ++q) op[q] = acc[q];
        } else {
            float* op = out + (size_t)row * F;
#pragma unroll
            for (int q = 0; q < 5; ++q) {
                atomicAdd(op + q * 4 + 0, acc[q].x);
                atomicAdd(op + q * 4 + 1, acc[q].y);
                atomicAdd(op + q * 4 + 2, acc[q].z);
                atomicAdd(op + q * 4 + 3, acc[q].w);
            }
        }
    }
}

// ---------------------------------------------------------------------------
// reduce the KSPLIT partial buffers; optionally fuse bias+relu.
// ---------------------------------------------------------------------------
template <int BIASRELU>
__global__ __launch_bounds__(256) void reduce_p(const float* __restrict__ P,
                                                const float* __restrict__ b,
                                                float* __restrict__ out) {
    int t = blockIdx.x * 256 + threadIdx.x;
    if (t >= NFLT4) return;
    float4 s = ((const float4*)P)[t];
    for (int k = 1; k < KSPLIT; ++k) {
        float4 v = ((const float4*)P)[(size_t)k * NFLT4 + t];
        s.x += v.x; s.y += v.y; s.z += v.z; s.w += v.w;
    }
    if (BIASRELU) {
        int f4 = t % (F / 4);
        float4 bv = ((const float4*)b)[f4];
        s.x = fmaxf(s.x + bv.x, 0.f);
        s.y = fmaxf(s.y + bv.y, 0.f);
        s.z = fmaxf(s.z + bv.z, 0.f);
        s.w = fmaxf(s.w + bv.w, 0.f);
    }
    ((float4*)out)[t] = s;
}

// ---------------------------------------------------------------------------
// out[i,f] = relu( relu( sum_g u[i,g]*W3[g,f] + b3[f] ) + x[i,f] )
// ---------------------------------------------------------------------------
__global__ __launch_bounds__(256) void final_fuse(const float* __restrict__ u,
                                                  const float* __restrict__ W3,
                                                  const float* __restrict__ b3,
                                                  const float* __restrict__ x,
                                                  float* __restrict__ out) {
    int t = blockIdx.x * 256 + threadIdx.x;
    if (t >= NN * DOUT) return;
    int i = t / DOUT, f = t % DOUT;
    const float* up = u + (size_t)i * F;
    float s = b3[f];
#pragma unroll
    for (int g = 0; g < F; ++g) s += up[g] * W3[g * DOUT + f];
    float h = fmaxf(s, 0.f);
    out[t] = fmaxf(h + x[t], 0.f);
}

// ---------------------------------------------------------------------------
extern "C" void kernel_launch(void* const* d_in, const int* in_sizes, int n_in,
                              void* d_out, int out_size, void* d_ws, size_t ws_size,
                              hipStream_t stream) {
    const float* x   = (const float*)d_in[0];
    const float* adj = (const float*)d_in[1];
    const float* W1  = (const float*)d_in[2];
    const float* b1  = (const float*)d_in[3];
    const float* W2  = (const float*)d_in[4];
    const float* b2  = (const float*)d_in[5];
    const float* W3  = (const float*)d_in[6];
    const float* b3  = (const float*)d_in[7];
    float* out = (float*)d_out;

    float* A = (float*)d_ws;            // N x F
    float* C = A + (size_t)NN * F;      // N x F
    float* P = C + (size_t)NN * F;      // KSPLIT x N x F partials (40 MB)
    const size_t nf_bytes = (size_t)NN * F * sizeof(float);
    const size_t need = nf_bytes * (2 + KSPLIT);

    const int blk_nf  = (NN * F + 255) / 256;        // 782
    const int blk_nf4 = (NFLT4 + 255) / 256;         // 196
    const int blk_no  = (NN * DOUT + 255) / 256;     // 5000
    dim3 agrid(ROWBLK, KSPLIT);                      // 79 x 50 = 3950 blocks

    if (ws_size >= need) {
        // Layer 1: h1 = relu(adj @ (x@W1) + b1)
        gemm_x_w1<<<blk_nf, 256, 0, stream>>>(x, W1, A);
        adjmm<0, 1><<<agrid, 256, 0, stream>>>(adj, A, P);
        reduce_p<1><<<blk_nf4, 256, 0, stream>>>(P, b1, C);

        // Layer 2: h2 = relu(adj @ (h1@W2) + b2)   (adj streamed in reverse)
        gemm_h_w2<<<blk_nf, 256, 0, stream>>>(C, W2, A);
        adjmm<1, 1><<<agrid, 256, 0, stream>>>(adj, A, P);
        reduce_p<1><<<blk_nf4, 256, 0, stream>>>(P, b2, C);

        // Layer 3 (reassociated): u = adj @ h2 ; out = relu(relu(u@W3+b3)+x)
        adjmm<0, 1><<<agrid, 256, 0, stream>>>(adj, C, P);
        reduce_p<0><<<blk_nf4, 256, 0, stream>>>(P, nullptr, A);
        final_fuse<<<blk_no, 256, 0, stream>>>(A, W3, b3, x, out);
    } else {
        // Fallback: atomic accumulation (3 NxF buffers only)
        float* B = P;  // only NxF of it used
        gemm_x_w1<<<blk_nf, 256, 0, stream>>>(x, W1, A);
        hipMemsetAsync(B, 0, nf_bytes, stream);
        adjmm<0, 0><<<agrid, 256, 0, stream>>>(adj, A, B);
        bias_relu<<<blk_nf, 256, 0, stream>>>(B, b1, C);

        gemm_h_w2<<<blk_nf, 256, 0, stream>>>(C, W2, A);
        hipMemsetAsync(B, 0, nf_bytes, stream);
        adjmm<1, 0><<<agrid, 256, 0, stream>>>(adj, A, B);
        bias_relu<<<blk_nf, 256, 0, stream>>>(B, b2, C);

        hipMemsetAsync(A, 0, nf_bytes, stream);
        adjmm<0, 0><<<agrid, 256, 0, stream>>>(adj, C, A);
        final_fuse<<<blk_no, 256, 0, stream>>>(A, W3, b3, x, out);
    }
}